// Round 4
// baseline (1117.094 us; speedup 1.0000x reference)
//
#include <hip/hip_runtime.h>
#include <cstdint>
#include <cstddef>

typedef _Float16 f16x8 __attribute__((ext_vector_type(8)));
typedef float    f32x4 __attribute__((ext_vector_type(4)));

#define TILE_M 128   // rows (points) per k4 block
#define WROWS  32    // rows per wave (4 waves/block)

// ---------------- K0: split fp32 weights into fp16 hi/lo, padded layouts ----
// W0p: [4][256][96] (K 66->96 pad)  W1p: [4][256][256]  W2p: [4][16][256] (3->16 rows)
// WlinP: [192][64] (K 63->64 pad)
__global__ __launch_bounds__(256)
void k0_split(const float* __restrict__ W0, const float* __restrict__ W1,
              const float* __restrict__ W2, const float* __restrict__ Wlin,
              _Float16* __restrict__ W0h, _Float16* __restrict__ W0l,
              _Float16* __restrict__ W1h, _Float16* __restrict__ W1l,
              _Float16* __restrict__ W2h, _Float16* __restrict__ W2l,
              _Float16* __restrict__ WlinH, _Float16* __restrict__ WlinL)
{
    int idx = blockIdx.x * 256 + threadIdx.x;
    if (idx < 4*256*96) {
        int k = idx % 96; int en = idx / 96;
        float v = (k < 66) ? W0[en*66 + k] : 0.f;
        _Float16 h = (_Float16)v;
        W0h[idx] = h; W0l[idx] = (_Float16)(v - (float)h);
    }
    if (idx < 4*256*256) {
        float v = W1[idx];
        _Float16 h = (_Float16)v;
        W1h[idx] = h; W1l[idx] = (_Float16)(v - (float)h);
    }
    if (idx < 4*16*256) {
        int k = idx % 256; int er = idx / 256;
        int e = er / 16; int r = er % 16;
        float v = (r < 3) ? W2[(e*3 + r)*256 + k] : 0.f;
        _Float16 h = (_Float16)v;
        W2h[idx] = h; W2l[idx] = (_Float16)(v - (float)h);
    }
    if (idx < 192*64) {
        int k = idx & 63; int cc = idx >> 6;
        float v = (k < 63) ? Wlin[cc*63 + k] : 0.f;
        _Float16 h = (_Float16)v;
        WlinH[idx] = h; WlinL[idx] = (_Float16)(v - (float)h);
    }
}

// ---------------- K1: per-point prep via mini-GEMM --------------------------
// Block = 128 points, 4 waves. Phase 1: lin = enc @ Wlin^T for ALL 192 channels
// via MFMA (avoids 756 divergent global loads/thread of the naive gather).
// Phase 2: gather 12 channels from LDS, softmax-combine, nearest/order build.
#define MFMA16(A,B,C) __builtin_amdgcn_mfma_f32_16x16x32_f16(A, B, C, 0, 0, 0)

__global__ __launch_bounds__(256)
void k1_prep(const float* __restrict__ X, const int* __restrict__ cid,
             const float* __restrict__ dist,
             const _Float16* __restrict__ WlinH, const _Float16* __restrict__ WlinL,
             const float* __restrict__ lambdas,
             float* __restrict__ combined, int* __restrict__ order,
             int* __restrict__ cnt, int N)
{
    __shared__ _Float16 lins[4][32][200];   // 51.2 KB, per-wave [32 rows][192+pad]
    __shared__ int hist[4];
    __shared__ int baseoff[4];
    int t = threadIdx.x;
    int wv = t >> 6, lane = t & 63, q = lane >> 4, lm = lane & 15;
    int blk = blockIdx.x;
    if (t < 4) hist[t] = 0;

    // ---- phase 1: enc[128x64] x WlinP^T[64x192] -> lins ----
    float xx[2][3];
    #pragma unroll
    for (int mt = 0; mt < 2; mt++) {
        int p = blk*128 + wv*32 + mt*16 + lm;
        bool v = (p < N);
        xx[mt][0] = v ? X[p*3+0] : 0.f;
        xx[mt][1] = v ? X[p*3+1] : 0.f;
        xx[mt][2] = v ? X[p*3+2] : 0.f;
    }
    f32x4 acc[2][12];
    #pragma unroll
    for (int mt = 0; mt < 2; mt++)
        #pragma unroll
        for (int nt = 0; nt < 12; nt++)
            acc[mt][nt] = (f32x4){0.f, 0.f, 0.f, 0.f};

    #pragma unroll
    for (int ks = 0; ks < 2; ks++) {
        f16x8 ah[2], al[2];
        #pragma unroll
        for (int mt = 0; mt < 2; mt++) {
            #pragma unroll
            for (int j = 0; j < 8; j++) {
                int c = ks*32 + q*8 + j;   // enc col: [x(3) | sin(30) | cos(30) | pad]
                float v;
                if (c >= 63) v = 0.f;
                else if (c < 3) v = xx[mt][c];
                else {
                    int is_sin = (c < 33);
                    int s = is_sin ? (c - 3) : (c - 33);
                    int f = s / 3;
                    int d = s - f*3;
                    float arg = xx[mt][d] * (float)(1 << f);
                    float sv, cv;
                    sincosf(arg, &sv, &cv);
                    v = is_sin ? sv : cv;
                }
                _Float16 h = (_Float16)v;
                ah[mt][j] = h;
                al[mt][j] = (_Float16)(v - (float)h);
            }
        }
        #pragma unroll
        for (int nt = 0; nt < 12; nt++) {
            f16x8 bh = *(const f16x8*)(WlinH + (nt*16 + lm)*64 + ks*32 + q*8);
            f16x8 bl = *(const f16x8*)(WlinL + (nt*16 + lm)*64 + ks*32 + q*8);
            #pragma unroll
            for (int mt = 0; mt < 2; mt++) {
                acc[mt][nt] = MFMA16(ah[mt], bh, acc[mt][nt]);
                acc[mt][nt] = MFMA16(ah[mt], bl, acc[mt][nt]);
                acc[mt][nt] = MFMA16(al[mt], bh, acc[mt][nt]);
            }
        }
    }
    #pragma unroll
    for (int mt = 0; mt < 2; mt++)
        #pragma unroll
        for (int nt = 0; nt < 12; nt++)
            #pragma unroll
            for (int r = 0; r < 4; r++)
                lins[wv][mt*16 + q*4 + r][nt*16 + lm] = (_Float16)acc[mt][nt][r];
    __syncthreads();

    // ---- phase 2: gather + softmax + order (threads 0..127, one point each) --
    int near = 0, lrank = 0; bool valid = false; int p = 0;
    if (t < 128) {
        p = blk*128 + t;
        valid = (p < N);
        if (valid) {
            float d[4];
            #pragma unroll
            for (int k = 0; k < 4; k++) d[k] = dist[(size_t)k*N + p];
            float dmin = d[0]; near = 0;
            #pragma unroll
            for (int k = 1; k < 4; k++) if (d[k] < dmin) { dmin = d[k]; near = k; }
            float lam = lambdas[near];
            float s[4], wgt[4];
            #pragma unroll
            for (int k = 0; k < 4; k++) s[k] = lam * expf(-lam * d[k]);
            float m = fmaxf(fmaxf(s[0], s[1]), fmaxf(s[2], s[3]));
            float ssum = 0.f;
            #pragma unroll
            for (int k = 0; k < 4; k++) { wgt[k] = expf(s[k] - m); ssum += wgt[k]; }
            float inv = 1.f / ssum;
            int4 c4 = *(const int4*)(cid + p*4);
            int cks[4] = {c4.x, c4.y, c4.z, c4.w};
            int wv2 = t >> 5, r2 = t & 31;
            float c0 = 0.f, c1 = 0.f, c2 = 0.f;
            #pragma unroll
            for (int k = 0; k < 4; k++) {
                float wk = wgt[k] * inv;
                int b = cks[k] * 3;
                c0 += wk * (float)lins[wv2][r2][b+0];
                c1 += wk * (float)lins[wv2][r2][b+1];
                c2 += wk * (float)lins[wv2][r2][b+2];
            }
            combined[p*3+0] = c0; combined[p*3+1] = c1; combined[p*3+2] = c2;
            lrank = atomicAdd(&hist[near], 1);
        }
    }
    __syncthreads();
    if (t < 4) baseoff[t] = atomicAdd(&cnt[t], hist[t]);
    __syncthreads();
    if (valid) order[(size_t)near*N + baseoff[near] + lrank] = p;
}

// ---------------- K4: fused 3-layer MLP, full hi/lo (3-pass) MFMA -----------
// Block = 4 waves x 32 rows = 128 points of ONE expert. B-frags stream from
// L1/L2 (all 4 waves issue IDENTICAL B addresses near-lockstep -> L1 reuse).
// Activations held in f32 LDS; A-frags split hi/lo on the fly, so all layers
// get 3-pass split precision (err ~1e-6 vs fp32 ref).
// MFMA 16x16x32_f16: A: m=lane&15, k=8*(lane>>4)+j ; B: n=lane&15, k=8*(lane>>4)+j
//                    D: n=lane&15, m=4*(lane>>4)+reg   (m89-verified mapping)
// hbuf stride 268 f32: read = conflict-free b128 phases; D-store 2-way (free).
// (stride 264 would make the 4 q-groups alias: 4*264 % 32 == 0 -> 4-way.)
__global__ __launch_bounds__(256, 1)
void k4_mlp(const float* __restrict__ X, const float* __restrict__ combined,
            const int* __restrict__ order, const int* __restrict__ cnt,
            const _Float16* __restrict__ W0h, const _Float16* __restrict__ W0l,
            const _Float16* __restrict__ W1h, const _Float16* __restrict__ W1l,
            const _Float16* __restrict__ W2h, const _Float16* __restrict__ W2l,
            float* __restrict__ out, int N, int tpe)
{
    __shared__ __align__(16) float hbuf[4][32][268];   // 134 KB -> 1 block/CU
    // expert-interleaved mapping: active tiles first, empty blocks drain at tail
    int e = blockIdx.x & 3;
    int tile = blockIdx.x >> 2;
    int count = cnt[e];
    int row0 = tile * TILE_M;
    if (row0 >= count) return;
    int wv   = threadIdx.x >> 6;
    int lane = threadIdx.x & 63;
    int q    = lane >> 4;      // k-slot group 0..3
    int lm   = lane & 15;      // m (A rows) / n (B cols)
    int wbase = row0 + wv * WROWS;
    const int* ord = order + (size_t)e * N + wbase;

    // hoist per-row point data for the 2 m-tiles this lane feeds (rows lm, lm+16)
    float xx[2][3], cb[2][3];
    #pragma unroll
    for (int mt = 0; mt < 2; mt++) {
        int r = mt*16 + lm;
        int pos = wbase + r;
        int p = (pos < count) ? ord[r] : 0;
        xx[mt][0] = X[p*3+0]; xx[mt][1] = X[p*3+1]; xx[mt][2] = X[p*3+2];
        cb[mt][0] = combined[p*3+0]; cb[mt][1] = combined[p*3+1]; cb[mt][2] = combined[p*3+2];
    }

    const _Float16* w0hb = W0h + e*(256*96);
    const _Float16* w0lb = W0l + e*(256*96);
    f32x4 acc[2][16];
    #pragma unroll
    for (int mt = 0; mt < 2; mt++)
        #pragma unroll
        for (int nt = 0; nt < 16; nt++)
            acc[mt][nt] = (f32x4){0.f, 0.f, 0.f, 0.f};

    // ---- layer 0: inp[66->96] x W0^T, A hi/lo + B hi/lo (3-pass) ----
    #pragma unroll
    for (int ks = 0; ks < 3; ks++) {
        f16x8 ah[2], al[2];
        #pragma unroll
        for (int mt = 0; mt < 2; mt++) {
            #pragma unroll
            for (int j = 0; j < 8; j++) {
                int c = ks*32 + q*8 + j;   // inp col: [comb(3)|x(3)|sin(30)|cos(30)|pad]
                float v;
                if (c >= 66) v = 0.f;
                else if (c < 3) v = (c==0) ? cb[mt][0] : ((c==1) ? cb[mt][1] : cb[mt][2]);
                else if (c < 6) v = (c==3) ? xx[mt][0] : ((c==4) ? xx[mt][1] : xx[mt][2]);
                else {
                    int is_sin = (c < 36);
                    int s = is_sin ? (c - 6) : (c - 36);
                    int f = s / 3;
                    int d = s - f*3;
                    float xd = (d==0) ? xx[mt][0] : ((d==1) ? xx[mt][1] : xx[mt][2]);
                    float arg = xd * (float)(1 << f);
                    float sv, cv;
                    sincosf(arg, &sv, &cv);
                    v = is_sin ? sv : cv;
                }
                _Float16 h = (_Float16)v;
                ah[mt][j] = h;
                al[mt][j] = (_Float16)(v - (float)h);
            }
        }
        #pragma unroll
        for (int nt = 0; nt < 16; nt++) {
            f16x8 bh = *(const f16x8*)(w0hb + (nt*16 + lm)*96 + ks*32 + q*8);
            f16x8 bl = *(const f16x8*)(w0lb + (nt*16 + lm)*96 + ks*32 + q*8);
            #pragma unroll
            for (int mt = 0; mt < 2; mt++) {
                acc[mt][nt] = MFMA16(ah[mt], bh, acc[mt][nt]);
                acc[mt][nt] = MFMA16(ah[mt], bl, acc[mt][nt]);
                acc[mt][nt] = MFMA16(al[mt], bh, acc[mt][nt]);
            }
        }
    }
    // relu -> h0 (f32) into wave-private LDS
    #pragma unroll
    for (int mt = 0; mt < 2; mt++)
        #pragma unroll
        for (int nt = 0; nt < 16; nt++)
            #pragma unroll
            for (int r = 0; r < 4; r++)
                hbuf[wv][mt*16 + q*4 + r][nt*16 + lm] = fmaxf(acc[mt][nt][r], 0.f);
    __syncthreads();

    // ---- layer 1: h0 x W1^T, A hi/lo (from f32 LDS, b128 reads) + B hi/lo ----
    const _Float16* w1hb = W1h + e*(256*256);
    const _Float16* w1lb = W1l + e*(256*256);
    #pragma unroll
    for (int mt = 0; mt < 2; mt++)
        #pragma unroll
        for (int nt = 0; nt < 16; nt++)
            acc[mt][nt] = (f32x4){0.f, 0.f, 0.f, 0.f};
    for (int ks = 0; ks < 8; ks++) {
        f16x8 ah[2], al[2];
        #pragma unroll
        for (int mt = 0; mt < 2; mt++) {
            const float* src = &hbuf[wv][mt*16 + lm][ks*32 + q*8];
            f32x4 va0 = *(const f32x4*)(src);      // ds_read_b128
            f32x4 va1 = *(const f32x4*)(src + 4);  // ds_read_b128
            #pragma unroll
            for (int j = 0; j < 8; j++) {
                float v = (j < 4) ? va0[j] : va1[j-4];
                _Float16 h = (_Float16)v;
                ah[mt][j] = h;
                al[mt][j] = (_Float16)(v - (float)h);
            }
        }
        #pragma unroll
        for (int nt = 0; nt < 16; nt++) {
            f16x8 bh = *(const f16x8*)(w1hb + (nt*16 + lm)*256 + ks*32 + q*8);
            f16x8 bl = *(const f16x8*)(w1lb + (nt*16 + lm)*256 + ks*32 + q*8);
            #pragma unroll
            for (int mt = 0; mt < 2; mt++) {
                acc[mt][nt] = MFMA16(ah[mt], bh, acc[mt][nt]);
                acc[mt][nt] = MFMA16(ah[mt], bl, acc[mt][nt]);
                acc[mt][nt] = MFMA16(al[mt], bh, acc[mt][nt]);
            }
        }
    }
    __syncthreads();
    // relu -> h1 (f32) overwrites hbuf
    #pragma unroll
    for (int mt = 0; mt < 2; mt++)
        #pragma unroll
        for (int nt = 0; nt < 16; nt++)
            #pragma unroll
            for (int r = 0; r < 4; r++)
                hbuf[wv][mt*16 + q*4 + r][nt*16 + lm] = fmaxf(acc[mt][nt][r], 0.f);
    __syncthreads();

    // ---- layer 2: h1 x W2^T (N=3 padded to 16), A hi/lo + B hi/lo ----
    const _Float16* w2hb = W2h + e*(16*256);
    const _Float16* w2lb = W2l + e*(16*256);
    f32x4 acc3[2];
    acc3[0] = (f32x4){0.f,0.f,0.f,0.f};
    acc3[1] = (f32x4){0.f,0.f,0.f,0.f};
    for (int ks = 0; ks < 8; ks++) {
        f16x8 ah[2], al[2];
        #pragma unroll
        for (int mt = 0; mt < 2; mt++) {
            const float* src = &hbuf[wv][mt*16 + lm][ks*32 + q*8];
            f32x4 va0 = *(const f32x4*)(src);
            f32x4 va1 = *(const f32x4*)(src + 4);
            #pragma unroll
            for (int j = 0; j < 8; j++) {
                float v = (j < 4) ? va0[j] : va1[j-4];
                _Float16 h = (_Float16)v;
                ah[mt][j] = h;
                al[mt][j] = (_Float16)(v - (float)h);
            }
        }
        f16x8 bh = *(const f16x8*)(w2hb + lm*256 + ks*32 + q*8);
        f16x8 bl = *(const f16x8*)(w2lb + lm*256 + ks*32 + q*8);
        #pragma unroll
        for (int mt = 0; mt < 2; mt++) {
            acc3[mt] = MFMA16(ah[mt], bh, acc3[mt]);
            acc3[mt] = MFMA16(ah[mt], bl, acc3[mt]);
            acc3[mt] = MFMA16(al[mt], bh, acc3[mt]);
        }
    }
    // epilogue: tanh, mask (X == -1,-1,-1 -> 0), scatter to out[pt][0..2]
    if (lm < 3) {
        #pragma unroll
        for (int mt = 0; mt < 2; mt++)
            #pragma unroll
            for (int r = 0; r < 4; r++) {
                int row = mt*16 + q*4 + r;
                int pos = wbase + row;
                if (pos < count) {
                    int p = ord[row];
                    float x0 = X[p*3+0], x1 = X[p*3+1], x2 = X[p*3+2];
                    float msk = (x0 == -1.f && x1 == -1.f && x2 == -1.f) ? 0.f : 1.f;
                    out[p*3 + lm] = tanhf(acc3[mt][r]) * msk;
                }
            }
    }
}

extern "C" void kernel_launch(void* const* d_in, const int* in_sizes, int n_in,
                              void* d_out, int out_size, void* d_ws, size_t ws_size,
                              hipStream_t stream)
{
    const float* X    = (const float*)d_in[0];
    const int*   cid  = (const int*)  d_in[1];
    const float* dist = (const float*)d_in[2];
    const float* Wlin = (const float*)d_in[3];
    const float* lam  = (const float*)d_in[4];
    const float* W0   = (const float*)d_in[5];
    const float* W1   = (const float*)d_in[6];
    const float* W2   = (const float*)d_in[7];
    float* out = (float*)d_out;
    int N = in_sizes[0] / 3;

    char* ws = (char*)d_ws;
    size_t off = 0;
    int* cnt = (int*)(ws + off);           off += 256;
    float* combined = (float*)(ws + off);  off += (size_t)N * 3 * sizeof(float);
    off = (off + 255) & ~(size_t)255;
    int* order = (int*)(ws + off);         off += (size_t)4 * N * sizeof(int);
    off = (off + 255) & ~(size_t)255;
    _Float16* W0h = (_Float16*)(ws + off); off += (size_t)4*256*96*2;
    _Float16* W0l = (_Float16*)(ws + off); off += (size_t)4*256*96*2;
    _Float16* W1h = (_Float16*)(ws + off); off += (size_t)4*256*256*2;
    _Float16* W1l = (_Float16*)(ws + off); off += (size_t)4*256*256*2;
    _Float16* W2h = (_Float16*)(ws + off); off += (size_t)4*16*256*2;
    _Float16* W2l = (_Float16*)(ws + off); off += (size_t)4*16*256*2;
    _Float16* WlinH = (_Float16*)(ws + off); off += (size_t)192*64*2;
    _Float16* WlinL = (_Float16*)(ws + off); off += (size_t)192*64*2;
    // total ws use ~15.6 MB

    hipMemsetAsync(cnt, 0, 4 * sizeof(int), stream);
    k0_split<<<dim3((4*256*256 + 255)/256), dim3(256), 0, stream>>>(
        W0, W1, W2, Wlin, W0h, W0l, W1h, W1l, W2h, W2l, WlinH, WlinL);
    k1_prep<<<dim3((N + 127)/128), dim3(256), 0, stream>>>(
        X, cid, dist, WlinH, WlinL, lam, combined, order, cnt, N);
    int tpe = (N + TILE_M - 1) / TILE_M;
    k4_mlp<<<dim3(4*tpe), dim3(256), 0, stream>>>(
        X, combined, order, cnt, W0h, W0l, W1h, W1l, W2h, W2l, out, N, tpe);
}